// Round 11
// baseline (270.332 us; speedup 1.0000x reference)
//
#include <hip/hip_runtime.h>

// HGCNConv on MI355X. Round 11: row-partitioned CSR build — hist and fill
// are split into 8 classes (class = blockIdx & 7 ~ XCD) each handling only
// its row slice, so every deg/pos/einfo cache line has a single writing XCD
// and L2 merges stores before writeback (round-10 showed 52 MB = E*64B write
// amplification from cross-XCD partial-line evictions). hyplinear reverted
// to the round-9-proven 64-rows/block shape. Everything else = round-10.
//
// ws word layout:
//   [0..95] hyp_bias, [96] ||hb||^2, [97] dtype flag (1=bf16, 0=f32)
//   [128 .. 128+E)                 einfo: packed uint (w_bf16<<16 | col16)
//   then  xt bf16 [N*96 ushorts]   (logmap0 output of HypLinear)
//   then  deg[N] int, off[N+1] int, pos[N] int, bsum[64], boff[64]

typedef __attribute__((ext_vector_type(8))) short short8;
typedef __attribute__((ext_vector_type(4))) float floatx4;

#define DIN 256
#define DOUT 96
#define MAXN 0.996f         // (1 - 4e-3)/sqrt(c)
#define EPS15 1e-15f
#define ATC (1.0f - 1e-7f)

__device__ __forceinline__ float us2f(unsigned short u) {
    unsigned int v = ((unsigned int)u) << 16;
    return __uint_as_float(v);
}
// float -> bf16 bits, round-to-nearest-even (pure bit ops)
__device__ __forceinline__ unsigned short f2us(float f) {
    unsigned int b = __float_as_uint(f);
    unsigned int r = (b + 0x7FFFu + ((b >> 16) & 1u)) >> 16;
    return (unsigned short)r;
}

// ---- init: dtype detect + hyp_bias = proj(expmap0(bias)), one wave --------
__global__ void init_kernel(const unsigned short* __restrict__ xraw,
                            const void* __restrict__ bias,
                            float* __restrict__ ws) {
    int l = threadIdx.x;  // 64 threads, one wave
    float v0 = us2f(xraw[l]);
    float v1 = us2f(xraw[64 + l]);
    int big = (!(fabsf(v0) < 1e4f)) || (!(fabsf(v1) < 1e4f));
    #pragma unroll
    for (int m = 32; m >= 1; m >>= 1) big |= __shfl_xor(big, m, 64);
    bool isb = !big;
    if (l == 0) ws[97] = isb ? 1.0f : 0.0f;

    float b0 = isb ? us2f(((const unsigned short*)bias)[l])
                   : ((const float*)bias)[l];
    float b1 = 0.0f;
    if (l < 32)
        b1 = isb ? us2f(((const unsigned short*)bias)[64 + l])
                 : ((const float*)bias)[64 + l];
    float n2 = b0 * b0 + b1 * b1;
    #pragma unroll
    for (int m = 32; m >= 1; m >>= 1) n2 += __shfl_xor(n2, m, 64);
    float bn = fmaxf(sqrtf(n2), EPS15);
    float ef = tanhf(bn) / bn;
    float hn = ef * sqrtf(n2);
    float s = (hn > MAXN) ? MAXN / fmaxf(hn, EPS15) : 1.0f;
    ws[l] = s * ef * b0;
    if (l < 32) ws[64 + l] = s * ef * b1;
    if (l == 0) { float v = s * hn; ws[96] = v * v; }
}

// ---- zero int/float words --------------------------------------------------
__global__ void zero_kernel(float* __restrict__ p, long n) {
    long i = (long)blockIdx.x * blockDim.x + threadIdx.x;
    long stride = (long)gridDim.x * blockDim.x;
    for (; i < n; i += stride) p[i] = 0.0f;
}

// ---- degree histogram, row-partitioned (class = blockIdx & 7 ~ XCD) -------
__global__ void hist_kernel(const int* __restrict__ erow,
                            int* __restrict__ deg, int E, int bound) {
    int cls = blockIdx.x & 7;
    int idx = blockIdx.x >> 3;
    int nper = gridDim.x >> 3;
    int lo = cls * bound, hi = lo + bound;
    int stride = nper * 256;
    for (int e = idx * 256 + threadIdx.x; e < E; e += stride) {
        int r = erow[e];
        if (r >= lo && r < hi) atomicAdd(&deg[r], 1);
    }
}

// ---- hierarchical scan: phase A (per-block sums of 1024 elems) ------------
__global__ void scanA_kernel(const int* __restrict__ deg,
                             int* __restrict__ bsum, int N) {
    int t = threadIdx.x, lane = t & 63, wv = t >> 6;
    int base = blockIdx.x * 1024 + t * 4;
    int v = 0;
    #pragma unroll
    for (int j = 0; j < 4; j++) {
        int i = base + j;
        if (i < N) v += deg[i];
    }
    #pragma unroll
    for (int m = 32; m >= 1; m >>= 1) v += __shfl_xor(v, m, 64);
    __shared__ int wsum[4];
    if (lane == 0) wsum[wv] = v;
    __syncthreads();
    if (t == 0) bsum[blockIdx.x] = wsum[0] + wsum[1] + wsum[2] + wsum[3];
}

// ---- phase B: one wave scans the block sums -------------------------------
__global__ void scanB_kernel(const int* __restrict__ bsum,
                             int* __restrict__ boff,
                             int* __restrict__ offN, int nb) {
    int lane = threadIdx.x;  // 64 threads
    int running = 0;
    for (int b = 0; b < nb; b += 64) {
        int i = b + lane;
        int v = (i < nb) ? bsum[i] : 0;
        int s = v;
        #pragma unroll
        for (int d = 1; d < 64; d <<= 1) {
            int t = __shfl_up(s, d, 64);
            if (lane >= d) s += t;
        }
        if (i < nb) boff[i] = running + s - v;
        running += __shfl(s, 63, 64);
    }
    if (lane == 0) *offN = running;
}

// ---- phase C: block-local exclusive scan + block offset -------------------
__global__ void scanC_kernel(const int* __restrict__ deg,
                             const int* __restrict__ boff,
                             int* __restrict__ off, int* __restrict__ pos,
                             int N) {
    int t = threadIdx.x, lane = t & 63, wv = t >> 6;
    int base = blockIdx.x * 1024 + t * 4;
    int v[4]; int s = 0;
    #pragma unroll
    for (int j = 0; j < 4; j++) {
        int i = base + j;
        v[j] = (i < N) ? deg[i] : 0;
        s += v[j];
    }
    int sc = s;
    #pragma unroll
    for (int d = 1; d < 64; d <<= 1) {
        int tt = __shfl_up(sc, d, 64);
        if (lane >= d) sc += tt;
    }
    __shared__ int wsum[4];
    if (lane == 63) wsum[wv] = sc;
    __syncthreads();
    int wo = 0;
    for (int k = 0; k < wv; k++) wo += wsum[k];
    int excl = boff[blockIdx.x] + wo + (sc - s);
    #pragma unroll
    for (int j = 0; j < 4; j++) {
        int i = base + j;
        if (i < N) { off[i] = excl; pos[i] = excl; }
        excl += v[j];
    }
}

// ---- CSR fill, row-partitioned: einfo[slot] = (w_bf16<<16) | col16 --------
__global__ void fill_kernel(const void* __restrict__ ew,
                            const int* __restrict__ erow,
                            const int* __restrict__ ecol,
                            float* __restrict__ ws,
                            int* __restrict__ pos,
                            unsigned int* __restrict__ einfo, int E, int bound) {
    const bool isb = ws[97] != 0.0f;
    int cls = blockIdx.x & 7;
    int idx = blockIdx.x >> 3;
    int nper = gridDim.x >> 3;
    int lo = cls * bound, hi = lo + bound;
    int stride = nper * 256;
    for (int e = idx * 256 + threadIdx.x; e < E; e += stride) {
        int r = erow[e];
        if (r >= lo && r < hi) {
            unsigned int wbits = isb ? (unsigned int)((const unsigned short*)ew)[e]
                                     : (unsigned int)f2us(((const float*)ew)[e]);
            int p = atomicAdd(&pos[r], 1);
            einfo[p] = (wbits << 16) | (unsigned int)ecol[e];
        }
    }
}

// ---- HypLinear: MFMA GEMM, W in LDS (fragment-swizzled), 64 rows/block ----
// (round-9-proven shape)
__global__ void hyplinear_kernel(const void* __restrict__ x,
                                 const void* __restrict__ wgt,
                                 float* __restrict__ ws,
                                 unsigned short* __restrict__ xtb, int N) {
    __shared__ uint4 Wl[3072];   // 48 KB

    const int t = threadIdx.x;
    const int lane = t & 63;
    const int wv = t >> 6;
    const int mrow = lane & 15;
    const int quad = lane >> 4;
    const bool isb = ws[97] != 0.0f;

    // stage W swizzled: global chunk g = c*32 + j (c=16f+mr, j=kt*4+q)
    // -> Wl[(f*8+kt)*64 + q*16 + mr]
    if (isb) {
        const uint4* wg = (const uint4*)wgt;
        #pragma unroll
        for (int i = 0; i < 12; i++) {
            int g = t + 256 * i;            // 3072 chunks
            int c = g >> 5, j = g & 31;
            int f = c >> 4, mr = c & 15;
            int kt = j >> 2, q = j & 3;
            Wl[(f * 8 + kt) * 64 + q * 16 + mr] = wg[g];
        }
    } else {
        const float* wgf = (const float*)wgt;
        #pragma unroll
        for (int i = 0; i < 12; i++) {
            int g = t + 256 * i;
            int c = g >> 5, j = g & 31;
            int f = c >> 4, mr = c & 15;
            int kt = j >> 2, q = j & 3;
            const float* src = wgf + (size_t)c * DIN + j * 8;
            unsigned short tmp[8];
            #pragma unroll
            for (int z = 0; z < 8; z++) tmp[z] = f2us(src[z]);
            Wl[(f * 8 + kt) * 64 + q * 16 + mr] = *(const uint4*)tmp;
        }
    }
    __syncthreads();

    const int r0 = (blockIdx.x * 4 + wv) * 16;
    if (r0 >= N) return;

    float hbl[6];
    #pragma unroll
    for (int f = 0; f < 6; f++) hbl[f] = ws[mrow + 16 * f];
    const float hb2 = ws[96];

    int xr = r0 + mrow; if (xr >= N) xr = N - 1;
    short8 afrag[8];
    if (isb) {
        const unsigned short* xrow = (const unsigned short*)x + (size_t)xr * DIN + quad * 8;
        #pragma unroll
        for (int kt = 0; kt < 8; kt++)
            afrag[kt] = *(const short8*)(xrow + kt * 32);
    } else {
        const float* xrow = (const float*)x + (size_t)xr * DIN + quad * 8;
        #pragma unroll
        for (int kt = 0; kt < 8; kt++) {
            short8 a;
            #pragma unroll
            for (int j = 0; j < 8; j++) a[j] = (short)f2us(xrow[kt * 32 + j]);
            afrag[kt] = a;
        }
    }

    float xn2p = 0.f;
    #pragma unroll
    for (int kt = 0; kt < 8; kt++)
        #pragma unroll
        for (int j = 0; j < 8; j++) {
            float v = us2f((unsigned short)afrag[kt][j]);
            xn2p = fmaf(v, v, xn2p);
        }
    xn2p += __shfl_xor(xn2p, 16, 64);
    xn2p += __shfl_xor(xn2p, 32, 64);

    floatx4 acc[6];
    #pragma unroll
    for (int f = 0; f < 6; f++) acc[f] = (floatx4){0.f, 0.f, 0.f, 0.f};
    #pragma unroll
    for (int f = 0; f < 6; f++) {
        #pragma unroll
        for (int kt = 0; kt < 8; kt++) {
            uint4 bw = Wl[(f * 8 + kt) * 64 + lane];
            short8 b = *(const short8*)&bw;
            acc[f] = __builtin_amdgcn_mfma_f32_16x16x32_bf16(afrag[kt], b, acc[f], 0, 0, 0);
        }
    }
    // D layout (m89-verified): acc[f][reg] = mx[row=quad*4+reg][col=mrow+16f]

    float mxn2[4], dmh[4];
    #pragma unroll
    for (int reg = 0; reg < 4; reg++) {
        float a2 = 0.f, ad = 0.f;
        #pragma unroll
        for (int f = 0; f < 6; f++) {
            float v = acc[f][reg];
            a2 = fmaf(v, v, a2);
            ad = fmaf(v, hbl[f], ad);
        }
        mxn2[reg] = a2; dmh[reg] = ad;
    }
    #pragma unroll
    for (int m = 8; m >= 1; m >>= 1)
        #pragma unroll
        for (int reg = 0; reg < 4; reg++) {
            mxn2[reg] += __shfl_xor(mxn2[reg], m, 64);
            dmh[reg]  += __shfl_xor(dmh[reg],  m, 64);
        }

    int sel = mrow & 3;
    float xn2  = __shfl(xn2p, quad * 4 + sel, 64);
    float wmx2 = mxn2[sel], wdmh = dmh[sel];

    float xn  = fmaxf(sqrtf(xn2), EPS15);
    float mxn = fmaxf(sqrtf(wmx2), EPS15);
    float g   = (mxn / xn) * atanhf(fminf(xn, ATC));
    float tg  = tanhf(g);
    float rs0 = tg / mxn;
    float rn  = rs0 * sqrtf(wmx2);
    float s1  = (rn > MAXN) ? MAXN / fmaxf(rn, EPS15) : 1.0f;
    float al  = s1 * rs0;
    float x2  = al * al * wmx2;
    float xy  = al * wdmh;
    float cA  = 1.0f + 2.0f * xy + hb2;
    float cB  = 1.0f - x2;
    float den = fmaxf(1.0f + 2.0f * xy + x2 * hb2, EPS15);
    float p   = cA * al / den;
    float qq  = cB / den;
    float o2  = p*p*wmx2 + 2.0f*p*qq*wdmh + qq*qq*hb2;
    float on  = sqrtf(fmaxf(o2, 0.0f));
    float s2  = (on > MAXN) ? MAXN / fmaxf(on, EPS15) : 1.0f;
    float pn  = fmaxf(s2 * on, EPS15);
    float F   = (atanhf(fminf(pn, ATC)) / pn) * s2;
    float Fp_m = F * p, Fq_m = F * qq;

    float Fp[4], Fq[4];
    #pragma unroll
    for (int reg = 0; reg < 4; reg++) {
        Fp[reg] = __shfl(Fp_m, quad * 16 + reg, 64);
        Fq[reg] = __shfl(Fq_m, quad * 16 + reg, 64);
    }

    #pragma unroll
    for (int reg = 0; reg < 4; reg++) {
        int row = r0 + quad * 4 + reg;
        if (row < N) {
            size_t base = (size_t)row * DOUT + mrow;
            #pragma unroll
            for (int f = 0; f < 6; f++)
                xtb[base + 16 * f] = f2us(fmaf(Fp[reg], acc[f][reg], Fq[reg] * hbl[f]));
        }
    }
}

// ---- aggregation v4: packed einfo, dword gather, 8-edge unroll ------------
__global__ void agg_kernel(const unsigned short* __restrict__ xtb,
                           const unsigned int* __restrict__ einfo,
                           const int* __restrict__ off,
                           float* __restrict__ ws,
                           void* __restrict__ out, int N) {
    int wv = threadIdx.x >> 6, lane = threadIdx.x & 63;
    int node = blockIdx.x * 4 + wv;
    if (node >= N) return;
    const bool isb = ws[97] != 0.0f;
    const bool act = lane < 48;   // lane l handles features 2l, 2l+1

    int s = off[node], e2 = off[node + 1];
    float acc0 = 0.f, acc1 = 0.f;

    for (int cs = s; cs < e2; cs += 64) {
        int cnt = e2 - cs; if (cnt > 64) cnt = 64;
        unsigned int my = (cs + lane < e2) ? einfo[cs + lane] : 0u;

        int j = 0;
        for (; j + 8 <= cnt; j += 8) {
            float w[8]; const unsigned int* sp[8];
            #pragma unroll
            for (int k = 0; k < 8; k++) {
                unsigned int ei = (unsigned int)__shfl((int)my, j + k, 64);
                w[k] = __uint_as_float(ei & 0xFFFF0000u);
                sp[k] = (const unsigned int*)(xtb + (size_t)(ei & 0xFFFFu) * DOUT);
            }
            unsigned int u[8];
            #pragma unroll
            for (int k = 0; k < 8; k++) u[k] = act ? sp[k][lane] : 0u;
            #pragma unroll
            for (int k = 0; k < 8; k++) {
                acc0 = fmaf(w[k], __uint_as_float(u[k] << 16), acc0);
                acc1 = fmaf(w[k], __uint_as_float(u[k] & 0xFFFF0000u), acc1);
            }
        }
        for (; j < cnt; j++) {
            unsigned int ei = (unsigned int)__shfl((int)my, j, 64);
            float w = __uint_as_float(ei & 0xFFFF0000u);
            unsigned int u = act
                ? ((const unsigned int*)(xtb + (size_t)(ei & 0xFFFFu) * DOUT))[lane] : 0u;
            acc0 = fmaf(w, __uint_as_float(u << 16), acc0);
            acc1 = fmaf(w, __uint_as_float(u & 0xFFFF0000u), acc1);
        }
    }

    // fused final chain: proj(expmap0(relu(logmap0(proj(expmap0(.))))))
    float u0 = acc0, u1 = acc1;
    float n2 = u0*u0 + u1*u1;
    #pragma unroll
    for (int m = 32; m >= 1; m >>= 1) n2 += __shfl_xor(n2, m, 64);
    float un = fmaxf(sqrtf(n2), EPS15);
    float ef = tanhf(un) / un;
    float p0 = ef * u0, p1 = ef * u1;
    float pnrm = ef * sqrtf(n2);
    float sc = (pnrm > MAXN) ? MAXN / fmaxf(pnrm, EPS15) : 1.0f;
    p0 *= sc; p1 *= sc; pnrm *= sc;
    float pncl = fmaxf(pnrm, EPS15);
    float lf = atanhf(fminf(pncl, ATC)) / pncl;
    float t0 = fmaxf(lf * p0, 0.0f), t1 = fmaxf(lf * p1, 0.0f);
    float tn2 = t0*t0 + t1*t1;
    #pragma unroll
    for (int m = 32; m >= 1; m >>= 1) tn2 += __shfl_xor(tn2, m, 64);
    float tn = fmaxf(sqrtf(tn2), EPS15);
    float ef2 = tanhf(tn) / tn;
    float en = ef2 * sqrtf(tn2);
    float s2 = (en > MAXN) ? MAXN / fmaxf(en, EPS15) : 1.0f;
    float scale = s2 * ef2;
    float v0 = scale * t0, v1 = scale * t1;

    if (act) {
        if (isb) {
            unsigned int pk = ((unsigned int)f2us(v1) << 16) | (unsigned int)f2us(v0);
            ((unsigned int*)((unsigned short*)out + (size_t)node * DOUT))[lane] = pk;
        } else {
            float2 fv; fv.x = v0; fv.y = v1;
            ((float2*)((float*)out + (size_t)node * DOUT))[lane] = fv;
        }
    }
}

extern "C" void kernel_launch(void* const* d_in, const int* in_sizes, int n_in,
                              void* d_out, int out_size, void* d_ws, size_t ws_size,
                              hipStream_t stream) {
    const void* x    = d_in[0];
    const void* wgt  = d_in[1];
    const void* bias = d_in[2];
    const void* ew   = d_in[3];
    const int* erow  = (const int*)d_in[4];
    const int* ecol  = (const int*)d_in[5];

    int N = out_size / DOUT;      // 50000
    int E = in_sizes[4];          // 800000
    size_t nd = (size_t)N * DOUT;
    int nb = (N + 1023) / 1024;   // scan blocks (49)
    int bound = (N + 7) / 8;      // rows per class slice

    float* wsf = (float*)d_ws;
    unsigned int* einfo = (unsigned int*)(wsf + 128);
    unsigned short* xtb = (unsigned short*)(wsf + 128 + (size_t)E);
    int* deg            = (int*)(xtb + nd);
    int* off            = deg + N;
    int* pos            = off + N + 1;
    int* bsum           = pos + N;
    int* boff           = bsum + 64;

    init_kernel<<<1, 64, 0, stream>>>((const unsigned short*)x, bias, wsf);
    zero_kernel<<<128, 256, 0, stream>>>((float*)deg, N);
    hist_kernel<<<416, 256, 0, stream>>>(erow, deg, E, bound);
    scanA_kernel<<<nb, 256, 0, stream>>>(deg, bsum, N);
    scanB_kernel<<<1, 64, 0, stream>>>(bsum, boff, off + N, nb);
    scanC_kernel<<<nb, 256, 0, stream>>>(deg, boff, off, pos, N);
    fill_kernel<<<416, 256, 0, stream>>>(ew, erow, ecol, wsf, pos, einfo, E, bound);
    hyplinear_kernel<<<(N + 63) / 64, 256, 0, stream>>>(x, wgt, wsf, xtb, N);
    agg_kernel<<<(N + 3) / 4, 256, 0, stream>>>(xtb, einfo, off, wsf, d_out, N);
}

// Round 12
// 227.152 us; speedup vs baseline: 1.1901x; 1.1901x over previous
//
#include <hip/hip_runtime.h>

// HGCNConv on MI355X. Round 12: launch-graph restructuring (bodies = r10):
//  (a) zero+init fused; (b) scanB folded into scanC (redundant in-LDS scan
//  of <=64 block sums); (c) fill and hyplinear fused into ONE kernel with
//  interleaved per-block roles so fill's scatter latency hides under
//  hyplinear's MFMA. 9 launches -> 6. hist/fill logic reverted to r10 form
//  (r11's row-partitioned variant regressed: 8x erow re-read).
//
// ws word layout:
//   [0..95] hyp_bias, [96] ||hb||^2, [97] dtype flag (1=bf16, 0=f32)
//   [128 .. 128+E)                 einfo: packed uint (w_bf16<<16 | col16)
//   then  xt bf16 [N*96 ushorts]   (logmap0 output of HypLinear)
//   then  deg[N] int, off[N+1] int, pos[N] int, bsum[64]

typedef __attribute__((ext_vector_type(8))) short short8;
typedef __attribute__((ext_vector_type(4))) float floatx4;

#define DIN 256
#define DOUT 96
#define MAXN 0.996f         // (1 - 4e-3)/sqrt(c)
#define EPS15 1e-15f
#define ATC (1.0f - 1e-7f)

__device__ __forceinline__ float us2f(unsigned short u) {
    unsigned int v = ((unsigned int)u) << 16;
    return __uint_as_float(v);
}
// float -> bf16 bits, round-to-nearest-even (pure bit ops)
__device__ __forceinline__ unsigned short f2us(float f) {
    unsigned int b = __float_as_uint(f);
    unsigned int r = (b + 0x7FFFu + ((b >> 16) & 1u)) >> 16;
    return (unsigned short)r;
}

// ---- fused: zero deg + dtype detect + hyp_bias ----------------------------
__global__ void initzero_kernel(const unsigned short* __restrict__ xraw,
                                const void* __restrict__ bias,
                                float* __restrict__ ws,
                                int* __restrict__ deg, int N) {
    int i = blockIdx.x * blockDim.x + threadIdx.x;
    int stride = gridDim.x * blockDim.x;
    for (int k = i; k < N; k += stride) deg[k] = 0;

    if (blockIdx.x == 0 && threadIdx.x < 64) {
        int l = threadIdx.x;  // wave 0
        float v0 = us2f(xraw[l]);
        float v1 = us2f(xraw[64 + l]);
        int big = (!(fabsf(v0) < 1e4f)) || (!(fabsf(v1) < 1e4f));
        #pragma unroll
        for (int m = 32; m >= 1; m >>= 1) big |= __shfl_xor(big, m, 64);
        bool isb = !big;
        if (l == 0) ws[97] = isb ? 1.0f : 0.0f;

        float b0 = isb ? us2f(((const unsigned short*)bias)[l])
                       : ((const float*)bias)[l];
        float b1 = 0.0f;
        if (l < 32)
            b1 = isb ? us2f(((const unsigned short*)bias)[64 + l])
                     : ((const float*)bias)[64 + l];
        float n2 = b0 * b0 + b1 * b1;
        #pragma unroll
        for (int m = 32; m >= 1; m >>= 1) n2 += __shfl_xor(n2, m, 64);
        float bn = fmaxf(sqrtf(n2), EPS15);
        float ef = tanhf(bn) / bn;
        float hn = ef * sqrtf(n2);
        float s = (hn > MAXN) ? MAXN / fmaxf(hn, EPS15) : 1.0f;
        ws[l] = s * ef * b0;
        if (l < 32) ws[64 + l] = s * ef * b1;
        if (l == 0) { float v = s * hn; ws[96] = v * v; }
    }
}

// ---- degree histogram (r10 form) ------------------------------------------
__global__ void hist_kernel(const int* __restrict__ erow,
                            int* __restrict__ deg, int E) {
    int e = blockIdx.x * blockDim.x + threadIdx.x;
    if (e < E) atomicAdd(&deg[erow[e]], 1);
}

// ---- scan phase A: per-block sums of 1024 elems ---------------------------
__global__ void scanA_kernel(const int* __restrict__ deg,
                             int* __restrict__ bsum, int N) {
    int t = threadIdx.x, lane = t & 63, wv = t >> 6;
    int base = blockIdx.x * 1024 + t * 4;
    int v = 0;
    #pragma unroll
    for (int j = 0; j < 4; j++) {
        int i = base + j;
        if (i < N) v += deg[i];
    }
    #pragma unroll
    for (int m = 32; m >= 1; m >>= 1) v += __shfl_xor(v, m, 64);
    __shared__ int wsum[4];
    if (lane == 0) wsum[wv] = v;
    __syncthreads();
    if (t == 0) bsum[blockIdx.x] = wsum[0] + wsum[1] + wsum[2] + wsum[3];
}

// ---- scan phase BC fused: redundant wave-scan of block sums + local scan --
// requires nb <= 64 (N <= 65536).
__global__ void scanBC_kernel(const int* __restrict__ deg,
                              const int* __restrict__ bsum,
                              int* __restrict__ off, int* __restrict__ pos,
                              int N, int nb) {
    __shared__ int sboff;
    __shared__ int stot;
    __shared__ int wsum[4];
    int t = threadIdx.x, lane = t & 63, wv = t >> 6;

    if (t < 64) {
        int v = (lane < nb) ? bsum[lane] : 0;
        int s = v;
        #pragma unroll
        for (int d = 1; d < 64; d <<= 1) {
            int tt = __shfl_up(s, d, 64);
            if (lane >= d) s += tt;
        }
        if (lane == (int)blockIdx.x) sboff = s - v;   // exclusive at this block
        if (lane == 63) stot = s;                     // grand total
    }
    __syncthreads();

    int base = blockIdx.x * 1024 + t * 4;
    int v[4]; int s = 0;
    #pragma unroll
    for (int j = 0; j < 4; j++) {
        int i = base + j;
        v[j] = (i < N) ? deg[i] : 0;
        s += v[j];
    }
    int sc = s;
    #pragma unroll
    for (int d = 1; d < 64; d <<= 1) {
        int tt = __shfl_up(sc, d, 64);
        if (lane >= d) sc += tt;
    }
    if (lane == 63) wsum[wv] = sc;
    __syncthreads();
    int wo = 0;
    for (int k = 0; k < wv; k++) wo += wsum[k];
    int excl = sboff + wo + (sc - s);
    #pragma unroll
    for (int j = 0; j < 4; j++) {
        int i = base + j;
        if (i < N) { off[i] = excl; pos[i] = excl; }
        excl += v[j];
    }
    if (blockIdx.x == (unsigned)(nb - 1) && t == 0) off[N] = stot;
}

// ---- fused fill + hyplinear ------------------------------------------------
// Roles per block: blocks [0, 2*Fb) alternate (even=hyp, odd=fill) so both
// kinds are co-resident per CU; blocks [2*Fb, 2*Fb+Hb-Fb) are hyp.
//   fill role (r10 body, grid-stride): einfo[pos[row]++] = (w16<<16)|col
//   hyp role (r9-proven body): MFMA GEMM with W staged swizzled in LDS.
__global__ void fillhyp_kernel(const void* __restrict__ x,
                               const void* __restrict__ wgt,
                               const void* __restrict__ ew,
                               const int* __restrict__ erow,
                               const int* __restrict__ ecol,
                               float* __restrict__ ws,
                               int* __restrict__ pos,
                               unsigned int* __restrict__ einfo,
                               unsigned short* __restrict__ xtb,
                               int N, int E, int Fb) {
    __shared__ uint4 Wl[3072];   // 48 KB (hyp role only)

    const int t = threadIdx.x;
    const bool isb = ws[97] != 0.0f;

    int b = blockIdx.x;
    bool isfill; int idx;
    if (b < 2 * Fb) { isfill = (b & 1); idx = b >> 1; }
    else            { isfill = false;   idx = b - Fb; }

    if (isfill) {
        int stride = Fb * 256;
        for (int e = idx * 256 + t; e < E; e += stride) {
            unsigned int wbits = isb ? (unsigned int)((const unsigned short*)ew)[e]
                                     : (unsigned int)f2us(((const float*)ew)[e]);
            int p = atomicAdd(&pos[erow[e]], 1);
            einfo[p] = (wbits << 16) | (unsigned int)ecol[e];
        }
        return;
    }

    // ---------------- hyp role (r9-proven) ----------------
    const int lane = t & 63;
    const int wv = t >> 6;
    const int mrow = lane & 15;
    const int quad = lane >> 4;

    // stage W swizzled: global chunk g = c*32 + j (c=16f+mr, j=kt*4+q)
    // -> Wl[(f*8+kt)*64 + q*16 + mr]
    if (isb) {
        const uint4* wg = (const uint4*)wgt;
        #pragma unroll
        for (int i = 0; i < 12; i++) {
            int g = t + 256 * i;            // 3072 chunks
            int c = g >> 5, j = g & 31;
            int f = c >> 4, mr = c & 15;
            int kt = j >> 2, q = j & 3;
            Wl[(f * 8 + kt) * 64 + q * 16 + mr] = wg[g];
        }
    } else {
        const float* wgf = (const float*)wgt;
        #pragma unroll
        for (int i = 0; i < 12; i++) {
            int g = t + 256 * i;
            int c = g >> 5, j = g & 31;
            int f = c >> 4, mr = c & 15;
            int kt = j >> 2, q = j & 3;
            const float* src = wgf + (size_t)c * DIN + j * 8;
            unsigned short tmp[8];
            #pragma unroll
            for (int z = 0; z < 8; z++) tmp[z] = f2us(src[z]);
            Wl[(f * 8 + kt) * 64 + q * 16 + mr] = *(const uint4*)tmp;
        }
    }
    __syncthreads();

    const int r0 = (idx * 4 + wv) * 16;
    if (r0 >= N) return;

    float hbl[6];
    #pragma unroll
    for (int f = 0; f < 6; f++) hbl[f] = ws[mrow + 16 * f];
    const float hb2 = ws[96];

    int xr = r0 + mrow; if (xr >= N) xr = N - 1;
    short8 afrag[8];
    if (isb) {
        const unsigned short* xrow = (const unsigned short*)x + (size_t)xr * DIN + quad * 8;
        #pragma unroll
        for (int kt = 0; kt < 8; kt++)
            afrag[kt] = *(const short8*)(xrow + kt * 32);
    } else {
        const float* xrow = (const float*)x + (size_t)xr * DIN + quad * 8;
        #pragma unroll
        for (int kt = 0; kt < 8; kt++) {
            short8 a;
            #pragma unroll
            for (int j = 0; j < 8; j++) a[j] = (short)f2us(xrow[kt * 32 + j]);
            afrag[kt] = a;
        }
    }

    float xn2p = 0.f;
    #pragma unroll
    for (int kt = 0; kt < 8; kt++)
        #pragma unroll
        for (int j = 0; j < 8; j++) {
            float v = us2f((unsigned short)afrag[kt][j]);
            xn2p = fmaf(v, v, xn2p);
        }
    xn2p += __shfl_xor(xn2p, 16, 64);
    xn2p += __shfl_xor(xn2p, 32, 64);

    floatx4 acc[6];
    #pragma unroll
    for (int f = 0; f < 6; f++) acc[f] = (floatx4){0.f, 0.f, 0.f, 0.f};
    #pragma unroll
    for (int f = 0; f < 6; f++) {
        #pragma unroll
        for (int kt = 0; kt < 8; kt++) {
            uint4 bw = Wl[(f * 8 + kt) * 64 + lane];
            short8 bfr = *(const short8*)&bw;
            acc[f] = __builtin_amdgcn_mfma_f32_16x16x32_bf16(afrag[kt], bfr, acc[f], 0, 0, 0);
        }
    }
    // D layout (m89-verified): acc[f][reg] = mx[row=quad*4+reg][col=mrow+16f]

    float mxn2[4], dmh[4];
    #pragma unroll
    for (int reg = 0; reg < 4; reg++) {
        float a2 = 0.f, ad = 0.f;
        #pragma unroll
        for (int f = 0; f < 6; f++) {
            float v = acc[f][reg];
            a2 = fmaf(v, v, a2);
            ad = fmaf(v, hbl[f], ad);
        }
        mxn2[reg] = a2; dmh[reg] = ad;
    }
    #pragma unroll
    for (int m = 8; m >= 1; m >>= 1)
        #pragma unroll
        for (int reg = 0; reg < 4; reg++) {
            mxn2[reg] += __shfl_xor(mxn2[reg], m, 64);
            dmh[reg]  += __shfl_xor(dmh[reg],  m, 64);
        }

    int sel = mrow & 3;
    float xn2  = __shfl(xn2p, quad * 4 + sel, 64);
    float wmx2 = mxn2[sel], wdmh = dmh[sel];

    float xn  = fmaxf(sqrtf(xn2), EPS15);
    float mxn = fmaxf(sqrtf(wmx2), EPS15);
    float g   = (mxn / xn) * atanhf(fminf(xn, ATC));
    float tg  = tanhf(g);
    float rs0 = tg / mxn;
    float rn  = rs0 * sqrtf(wmx2);
    float s1  = (rn > MAXN) ? MAXN / fmaxf(rn, EPS15) : 1.0f;
    float al  = s1 * rs0;
    float x2  = al * al * wmx2;
    float xy  = al * wdmh;
    float cA  = 1.0f + 2.0f * xy + hb2;
    float cB  = 1.0f - x2;
    float den = fmaxf(1.0f + 2.0f * xy + x2 * hb2, EPS15);
    float p   = cA * al / den;
    float qq  = cB / den;
    float o2  = p*p*wmx2 + 2.0f*p*qq*wdmh + qq*qq*hb2;
    float on  = sqrtf(fmaxf(o2, 0.0f));
    float s2  = (on > MAXN) ? MAXN / fmaxf(on, EPS15) : 1.0f;
    float pn  = fmaxf(s2 * on, EPS15);
    float F   = (atanhf(fminf(pn, ATC)) / pn) * s2;
    float Fp_m = F * p, Fq_m = F * qq;

    float Fp[4], Fq[4];
    #pragma unroll
    for (int reg = 0; reg < 4; reg++) {
        Fp[reg] = __shfl(Fp_m, quad * 16 + reg, 64);
        Fq[reg] = __shfl(Fq_m, quad * 16 + reg, 64);
    }

    #pragma unroll
    for (int reg = 0; reg < 4; reg++) {
        int row = r0 + quad * 4 + reg;
        if (row < N) {
            size_t base = (size_t)row * DOUT + mrow;
            #pragma unroll
            for (int f = 0; f < 6; f++)
                xtb[base + 16 * f] = f2us(fmaf(Fp[reg], acc[f][reg], Fq[reg] * hbl[f]));
        }
    }
}

// ---- aggregation (r10 body): packed einfo, dword gather, 8-edge unroll ----
__global__ void agg_kernel(const unsigned short* __restrict__ xtb,
                           const unsigned int* __restrict__ einfo,
                           const int* __restrict__ off,
                           float* __restrict__ ws,
                           void* __restrict__ out, int N) {
    int wv = threadIdx.x >> 6, lane = threadIdx.x & 63;
    int node = blockIdx.x * 4 + wv;
    if (node >= N) return;
    const bool isb = ws[97] != 0.0f;
    const bool act = lane < 48;   // lane l handles features 2l, 2l+1

    int s = off[node], e2 = off[node + 1];
    float acc0 = 0.f, acc1 = 0.f;

    for (int cs = s; cs < e2; cs += 64) {
        int cnt = e2 - cs; if (cnt > 64) cnt = 64;
        unsigned int my = (cs + lane < e2) ? einfo[cs + lane] : 0u;

        int j = 0;
        for (; j + 8 <= cnt; j += 8) {
            float w[8]; const unsigned int* sp[8];
            #pragma unroll
            for (int k = 0; k < 8; k++) {
                unsigned int ei = (unsigned int)__shfl((int)my, j + k, 64);
                w[k] = __uint_as_float(ei & 0xFFFF0000u);
                sp[k] = (const unsigned int*)(xtb + (size_t)(ei & 0xFFFFu) * DOUT);
            }
            unsigned int u[8];
            #pragma unroll
            for (int k = 0; k < 8; k++) u[k] = act ? sp[k][lane] : 0u;
            #pragma unroll
            for (int k = 0; k < 8; k++) {
                acc0 = fmaf(w[k], __uint_as_float(u[k] << 16), acc0);
                acc1 = fmaf(w[k], __uint_as_float(u[k] & 0xFFFF0000u), acc1);
            }
        }
        for (; j < cnt; j++) {
            unsigned int ei = (unsigned int)__shfl((int)my, j, 64);
            float w = __uint_as_float(ei & 0xFFFF0000u);
            unsigned int u = act
                ? ((const unsigned int*)(xtb + (size_t)(ei & 0xFFFFu) * DOUT))[lane] : 0u;
            acc0 = fmaf(w, __uint_as_float(u << 16), acc0);
            acc1 = fmaf(w, __uint_as_float(u & 0xFFFF0000u), acc1);
        }
    }

    // fused final chain: proj(expmap0(relu(logmap0(proj(expmap0(.))))))
    float u0 = acc0, u1 = acc1;
    float n2 = u0*u0 + u1*u1;
    #pragma unroll
    for (int m = 32; m >= 1; m >>= 1) n2 += __shfl_xor(n2, m, 64);
    float un = fmaxf(sqrtf(n2), EPS15);
    float ef = tanhf(un) / un;
    float p0 = ef * u0, p1 = ef * u1;
    float pnrm = ef * sqrtf(n2);
    float sc = (pnrm > MAXN) ? MAXN / fmaxf(pnrm, EPS15) : 1.0f;
    p0 *= sc; p1 *= sc; pnrm *= sc;
    float pncl = fmaxf(pnrm, EPS15);
    float lf = atanhf(fminf(pncl, ATC)) / pncl;
    float t0 = fmaxf(lf * p0, 0.0f), t1 = fmaxf(lf * p1, 0.0f);
    float tn2 = t0*t0 + t1*t1;
    #pragma unroll
    for (int m = 32; m >= 1; m >>= 1) tn2 += __shfl_xor(tn2, m, 64);
    float tn = fmaxf(sqrtf(tn2), EPS15);
    float ef2 = tanhf(tn) / tn;
    float en = ef2 * sqrtf(tn2);
    float s2 = (en > MAXN) ? MAXN / fmaxf(en, EPS15) : 1.0f;
    float scale = s2 * ef2;
    float v0 = scale * t0, v1 = scale * t1;

    if (act) {
        if (isb) {
            unsigned int pk = ((unsigned int)f2us(v1) << 16) | (unsigned int)f2us(v0);
            ((unsigned int*)((unsigned short*)out + (size_t)node * DOUT))[lane] = pk;
        } else {
            float2 fv; fv.x = v0; fv.y = v1;
            ((float2*)((float*)out + (size_t)node * DOUT))[lane] = fv;
        }
    }
}

extern "C" void kernel_launch(void* const* d_in, const int* in_sizes, int n_in,
                              void* d_out, int out_size, void* d_ws, size_t ws_size,
                              hipStream_t stream) {
    const void* x    = d_in[0];
    const void* wgt  = d_in[1];
    const void* bias = d_in[2];
    const void* ew   = d_in[3];
    const int* erow  = (const int*)d_in[4];
    const int* ecol  = (const int*)d_in[5];

    int N = out_size / DOUT;      // 50000
    int E = in_sizes[4];          // 800000
    size_t nd = (size_t)N * DOUT;
    int nb = (N + 1023) / 1024;   // scan blocks (49), must be <= 64

    float* wsf = (float*)d_ws;
    unsigned int* einfo = (unsigned int*)(wsf + 128);
    unsigned short* xtb = (unsigned short*)(wsf + 128 + (size_t)E);
    int* deg            = (int*)(xtb + nd);
    int* off            = deg + N;
    int* pos            = off + N + 1;
    int* bsum           = pos + N;

    int Hb = (N + 63) / 64;       // hyplinear blocks (782)
    int Fb = (Hb + 1) / 2;        // fill blocks (391)

    initzero_kernel<<<128, 256, 0, stream>>>((const unsigned short*)x, bias, wsf, deg, N);
    hist_kernel<<<(E + 255) / 256, 256, 0, stream>>>(erow, deg, E);
    scanA_kernel<<<nb, 256, 0, stream>>>(deg, bsum, N);
    scanBC_kernel<<<nb, 256, 0, stream>>>(deg, bsum, off, pos, N, nb);
    fillhyp_kernel<<<Hb + Fb, 256, 0, stream>>>(x, wgt, ew, erow, ecol, wsf,
                                                pos, einfo, xtb, N, E, Fb);
    agg_kernel<<<(N + 3) / 4, 256, 0, stream>>>(xtb, einfo, off, wsf, d_out, N);
}